// Round 3
// baseline (261.368 us; speedup 1.0000x reference)
//
#include <hip/hip_runtime.h>

typedef float f4 __attribute__((ext_vector_type(4)));
typedef f4 f4u __attribute__((aligned(4)));   // 4B-aligned float4 (HW supports dword-aligned dwordx4)

// ---------------------------------------------------------------------------
// Single fused kernel: one block per segment.
//  1. Block computes its own exclusive offset: sum(lengths[0..s)) — lengths is
//     8 KB, L2-resident, ~8 coalesced ints/thread + wave/LDS reduce. Removes
//     the serial 1-block prefix-sum kernel.
//  2. Streams the segment's output as float4: each output float4 whose 4 cols
//     are all plain-x (c in [1,125], ~97%) is ONE unaligned float4 load from
//     x (contiguous, coalesced) + one aligned float4 store. Rare float4s that
//     contain the pos column / cross a row boundary take a scalar path
//     (~2 lanes per wave). No LDS staging, no barriers in the hot loop.
// ---------------------------------------------------------------------------
__global__ __launch_bounds__(256) void emb_kernel(const float* __restrict__ x,
                                                  const int* __restrict__ lengths,
                                                  float* __restrict__ out) {
    const int s = blockIdx.x;
    const int tid = threadIdx.x;

    // ---- exclusive prefix offset for this segment ----
    int partial = 0;
    for (int i = tid; i < s; i += 256) partial += lengths[i];
    #pragma unroll
    for (int d = 32; d > 0; d >>= 1) partial += __shfl_xor(partial, d, 64);

    __shared__ int wred[4];
    __shared__ int s_off;
    if ((tid & 63) == 0) wred[tid >> 6] = partial;
    __syncthreads();
    if (tid == 0) s_off = wred[0] + wred[1] + wred[2] + wred[3];
    __syncthreads();

    const int off = s_off;
    const int L = lengths[s];
    if (L <= 0) return;
    const float invL = 1.0f / (float)L;

    const float* __restrict__ xs = x + (size_t)off * 128;
    float* __restrict__ os = out + (size_t)off * 129;
    const int E = L * 129;

    if ((off & 3) == 0) {
        f4* __restrict__ o4 = (f4*)os;            // 16B-aligned (off%4==0)
        const int n4 = E >> 2;
        for (int i = tid; i < n4; i += 256) {
            const int e = i << 2;
            const int row = e / 129;               // magic-mul (const divisor)
            const int c = e - row * 129;
            if ((unsigned)(c - 1) <= 124u) {
                // cols c..c+3 are all x-columns of the same row:
                // one unaligned (4B-aligned) contiguous float4 load.
                o4[i] = *(const f4u*)(xs + row * 128 + (c - 1));
            } else {
                // contains the pos column and/or crosses a row boundary.
                float vals[4];
                #pragma unroll
                for (int k = 0; k < 4; ++k) {
                    int cc = c + k, r = row;
                    if (cc >= 129) { cc -= 129; r += 1; }  // at most one wrap
                    vals[k] = (cc == 0) ? (float)(r + 1) * invL
                                        : xs[r * 128 + (cc - 1)];
                }
                f4 v; v.x = vals[0]; v.y = vals[1]; v.z = vals[2]; v.w = vals[3];
                o4[i] = v;
            }
        }
        // tail if E % 4 != 0 (general ragged case)
        for (int e = (n4 << 2) + tid; e < E; e += 256) {
            const int row = e / 129;
            const int c = e - row * 129;
            os[e] = (c == 0) ? (float)(row + 1) * invL
                             : xs[row * 128 + (c - 1)];
        }
    } else {
        // unaligned segment base (general ragged case): scalar fallback
        for (int e = tid; e < E; e += 256) {
            const int row = e / 129;
            const int c = e - row * 129;
            os[e] = (c == 0) ? (float)(row + 1) * invL
                             : xs[row * 128 + (c - 1)];
        }
    }
}

extern "C" void kernel_launch(void* const* d_in, const int* in_sizes, int n_in,
                              void* d_out, int out_size, void* d_ws, size_t ws_size,
                              hipStream_t stream) {
    const float* x = (const float*)d_in[0];
    const int* lengths = (const int*)d_in[1];
    const int n_seg = in_sizes[1];

    emb_kernel<<<n_seg, 256, 0, stream>>>(x, lengths, (float*)d_out);
}

// Round 4
// 231.633 us; speedup vs baseline: 1.1284x; 1.1284x over previous
//
#include <hip/hip_runtime.h>

typedef float f4 __attribute__((ext_vector_type(4)));

// ---------------------------------------------------------------------------
// One block per segment, 256 threads = 4 waves. Barrier-free streaming:
// each WAVE owns a private 8-row LDS buffer (8*129 floats) and pipelines
//   aligned f4 global loads -> ds_write scatter (output layout, +1 shift,
//   pos col) -> ds_read_b128 flat -> aligned f4 global stores
// with NO __syncthreads in the hot loop (intra-wave DS ordering guarantees
// the read-after-write and write-after-read hazards on the private buffer).
// Both HBM streams are pure contiguous 16B-aligned float4 — copy-kernel
// shaped. Offsets are computed per-block from lengths (L2-resident, cheap).
// ---------------------------------------------------------------------------
__global__ __launch_bounds__(256) void emb_kernel(const float* __restrict__ x,
                                                  const int* __restrict__ lengths,
                                                  float* __restrict__ out) {
    __shared__ alignas(16) float lt[4 * 1032];   // 16.5 KB: one buffer per wave
    __shared__ int wred[4];
    __shared__ int s_off;

    const int s = blockIdx.x;
    const int tid = threadIdx.x;

    // ---- exclusive prefix offset for this segment (general ragged case) ----
    int partial = 0;
    for (int i = tid; i < s; i += 256) partial += lengths[i];
    #pragma unroll
    for (int d = 32; d > 0; d >>= 1) partial += __shfl_xor(partial, d, 64);
    if ((tid & 63) == 0) wred[tid >> 6] = partial;
    __syncthreads();
    if (tid == 0) s_off = wred[0] + wred[1] + wred[2] + wred[3];
    __syncthreads();

    const int off = s_off;
    const int L = lengths[s];
    if (L <= 0) return;
    const float invL = 1.0f / (float)L;

    const float* __restrict__ xs = x + (size_t)off * 128;
    float* __restrict__ os = out + (size_t)off * 129;

    const int wave = tid >> 6;
    const int lane = tid & 63;
    float* __restrict__ lb = lt + wave * 1032;

    // fast path needs the output segment base 16B-aligned: off % 4 == 0
    const int nt = ((off & 3) == 0) ? (L >> 5) : 0;   // 32-row block tiles

    for (int t = 0; t < nt; ++t) {
        const int r0 = t * 32 + wave * 8;             // this wave's 8 rows
        const f4* __restrict__ src = (const f4*)(xs + (size_t)r0 * 128);
        const f4 v0 = src[lane];
        const f4 v1 = src[lane + 64];
        const f4 v2 = src[lane + 128];
        const f4 v3 = src[lane + 192];

        // scatter into output-layout LDS (row-local +1 column shift)
        {
            const int q = lane;
            float* d = &lb[(q >> 5) * 129 + 1 + ((q & 31) << 2)];
            d[0] = v0.x; d[1] = v0.y; d[2] = v0.z; d[3] = v0.w;
        }
        {
            const int q = lane + 64;
            float* d = &lb[(q >> 5) * 129 + 1 + ((q & 31) << 2)];
            d[0] = v1.x; d[1] = v1.y; d[2] = v1.z; d[3] = v1.w;
        }
        {
            const int q = lane + 128;
            float* d = &lb[(q >> 5) * 129 + 1 + ((q & 31) << 2)];
            d[0] = v2.x; d[1] = v2.y; d[2] = v2.z; d[3] = v2.w;
        }
        {
            const int q = lane + 192;
            float* d = &lb[(q >> 5) * 129 + 1 + ((q & 31) << 2)];
            d[0] = v3.x; d[1] = v3.y; d[2] = v3.z; d[3] = v3.w;
        }
        if (lane < 8) lb[lane * 129] = (float)(r0 + lane + 1) * invL;

        // flat read-back + aligned streaming store (1032 floats = 258 f4)
        const f4* __restrict__ l4 = (const f4*)lb;
        f4* __restrict__ o4 = (f4*)os + (size_t)258 * (4 * t + wave);
        o4[lane]       = l4[lane];
        o4[lane + 64]  = l4[lane + 64];
        o4[lane + 128] = l4[lane + 128];
        o4[lane + 192] = l4[lane + 192];
        if (lane < 2) o4[256 + lane] = l4[256 + lane];
    }

    // tail rows / unaligned segment base: scalar fallback (general ragged)
    const int e0 = nt * 32 * 129;
    const int E = L * 129;
    for (int e = e0 + tid; e < E; e += 256) {
        const int row = e / 129;
        const int c = e - row * 129;
        os[e] = (c == 0) ? (float)(row + 1) * invL
                         : xs[(size_t)row * 128 + (c - 1)];
    }
}

extern "C" void kernel_launch(void* const* d_in, const int* in_sizes, int n_in,
                              void* d_out, int out_size, void* d_ws, size_t ws_size,
                              hipStream_t stream) {
    const float* x = (const float*)d_in[0];
    const int* lengths = (const int*)d_in[1];
    const int n_seg = in_sizes[1];

    emb_kernel<<<n_seg, 256, 0, stream>>>(x, lengths, (float*)d_out);
}

// Round 5
// 223.864 us; speedup vs baseline: 1.1675x; 1.0347x over previous
//
#include <hip/hip_runtime.h>

typedef float f4 __attribute__((ext_vector_type(4)));

// ---------------------------------------------------------------------------
// One block per segment, 256 threads = 4 waves, barrier-free hot loop.
// Wave chunk = 16 rows: loads = 16*128 floats = 8192 B (128 full cache lines),
// stores = 16*129 floats = 8256 B (exactly 129 full 64B lines). With
// off % 16 == 0 every global load AND store instruction is 64B-line-aligned
// and full-line -> no partial-line write-allocate traffic. Wave-private LDS
// buffer absorbs the +1 column shift; next tile's loads are software-
// prefetched into registers while the current tile drains; stores are
// non-temporal (streaming, no L2 allocate).
// ---------------------------------------------------------------------------
__global__ __launch_bounds__(256) void emb_kernel(const float* __restrict__ x,
                                                  const int* __restrict__ lengths,
                                                  float* __restrict__ out) {
    __shared__ alignas(16) float lt[4 * 2064];   // 33 KB: 16-row buffer per wave
    __shared__ int wred[4];
    __shared__ int s_off;

    const int s = blockIdx.x;
    const int tid = threadIdx.x;

    // ---- exclusive prefix offset for this segment (general ragged case) ----
    int partial = 0;
    for (int i = tid; i < s; i += 256) partial += lengths[i];
    #pragma unroll
    for (int d = 32; d > 0; d >>= 1) partial += __shfl_xor(partial, d, 64);
    if ((tid & 63) == 0) wred[tid >> 6] = partial;
    __syncthreads();
    if (tid == 0) s_off = wred[0] + wred[1] + wred[2] + wred[3];
    __syncthreads();

    const int off = s_off;
    const int L = lengths[s];
    if (L <= 0) return;
    const float invL = 1.0f / (float)L;

    const float* __restrict__ xs = x + (size_t)off * 128;
    float* __restrict__ os = out + (size_t)off * 129;

    const int wave = tid >> 6;
    const int lane = tid & 63;
    float* __restrict__ lb = lt + wave * 2064;

    // fast path: off % 16 == 0 makes both streams 64B-line-aligned
    const int nt64 = ((off & 15) == 0) ? (L >> 6) : 0;   // 64-row block tiles

    if (nt64 > 0) {
        const f4* __restrict__ xs4 = (const f4*)xs;
        f4 a[8];
        {   // prologue: prefetch tile 0 (this wave's 16 rows = 512 f4)
            const f4* src = xs4 + (size_t)(16 * wave) * 32;
            #pragma unroll
            for (int p = 0; p < 8; ++p) a[p] = src[lane + 64 * p];
        }
        for (int t = 0; t < nt64; ++t) {
            const int r0 = 64 * t + 16 * wave;

            // scatter regs -> LDS in output layout (+1 col shift)
            #pragma unroll
            for (int p = 0; p < 8; ++p) {
                const int q = lane + 64 * p;      // f4 index in 16x128 tile
                const int r = q >> 5;
                const int k = q & 31;
                float* d = &lb[r * 129 + 1 + 4 * k];
                d[0] = a[p].x; d[1] = a[p].y; d[2] = a[p].z; d[3] = a[p].w;
            }
            if (lane < 16) lb[lane * 129] = (float)(r0 + lane + 1) * invL;

            // software-prefetch next tile's loads (independent of drain below)
            if (t + 1 < nt64) {
                const f4* src = xs4 + (size_t)(64 * (t + 1) + 16 * wave) * 32;
                #pragma unroll
                for (int p = 0; p < 8; ++p) a[p] = src[lane + 64 * p];
            }

            // drain: flat LDS read + full-line non-temporal stores
            const f4* __restrict__ l4 = (const f4*)lb;
            f4* __restrict__ o4 = (f4*)(os + (size_t)r0 * 129);
            #pragma unroll
            for (int p = 0; p < 8; ++p)
                __builtin_nontemporal_store(l4[lane + 64 * p], &o4[lane + 64 * p]);
            if (lane < 4)
                __builtin_nontemporal_store(l4[512 + lane], &o4[512 + lane]);
        }
    }

    // tail rows / unaligned segment base: scalar fallback (general ragged)
    const int e0 = nt64 * 64 * 129;
    const int E = L * 129;
    for (int e = e0 + tid; e < E; e += 256) {
        const int row = e / 129;
        const int c = e - row * 129;
        os[e] = (c == 0) ? (float)(row + 1) * invL
                         : xs[(size_t)row * 128 + (c - 1)];
    }
}

extern "C" void kernel_launch(void* const* d_in, const int* in_sizes, int n_in,
                              void* d_out, int out_size, void* d_ws, size_t ws_size,
                              hipStream_t stream) {
    const float* x = (const float*)d_in[0];
    const int* lengths = (const int*)d_in[1];
    const int n_seg = in_sizes[1];

    emb_kernel<<<n_seg, 256, 0, stream>>>(x, lengths, (float*)d_out);
}

// Round 6
// 222.328 us; speedup vs baseline: 1.1756x; 1.0069x over previous
//
#include <hip/hip_runtime.h>

typedef float f4 __attribute__((ext_vector_type(4)));

// ---------------------------------------------------------------------------
// One block per segment, 256 threads = 4 waves, barrier-free hot loop.
// Wave chunk = 16 rows: loads = 16*128 floats = 8192 B (128 full cache lines),
// stores = 16*129 floats = 8256 B (exactly 129 full 64B lines). With
// off % 16 == 0 every global load AND store instruction is 64B-line-aligned
// and full-line. Wave-private LDS buffer absorbs the +1 column shift; next
// tile's loads are software-prefetched into registers while the current tile
// drains. R6: REGULAR cached stores (vs R5's non-temporal) — single-variable
// test of the store path; fill (6.7 TB/s) and m13 copy (6.29 TB/s) both use
// the cached write-back path.
// ---------------------------------------------------------------------------
__global__ __launch_bounds__(256) void emb_kernel(const float* __restrict__ x,
                                                  const int* __restrict__ lengths,
                                                  float* __restrict__ out) {
    __shared__ alignas(16) float lt[4 * 2064];   // 33 KB: 16-row buffer per wave
    __shared__ int wred[4];
    __shared__ int s_off;

    const int s = blockIdx.x;
    const int tid = threadIdx.x;

    // ---- exclusive prefix offset for this segment (general ragged case) ----
    int partial = 0;
    for (int i = tid; i < s; i += 256) partial += lengths[i];
    #pragma unroll
    for (int d = 32; d > 0; d >>= 1) partial += __shfl_xor(partial, d, 64);
    if ((tid & 63) == 0) wred[tid >> 6] = partial;
    __syncthreads();
    if (tid == 0) s_off = wred[0] + wred[1] + wred[2] + wred[3];
    __syncthreads();

    const int off = s_off;
    const int L = lengths[s];
    if (L <= 0) return;
    const float invL = 1.0f / (float)L;

    const float* __restrict__ xs = x + (size_t)off * 128;
    float* __restrict__ os = out + (size_t)off * 129;

    const int wave = tid >> 6;
    const int lane = tid & 63;
    float* __restrict__ lb = lt + wave * 2064;

    // fast path: off % 16 == 0 makes both streams 64B-line-aligned
    const int nt64 = ((off & 15) == 0) ? (L >> 6) : 0;   // 64-row block tiles

    if (nt64 > 0) {
        const f4* __restrict__ xs4 = (const f4*)xs;
        f4 a[8];
        {   // prologue: prefetch tile 0 (this wave's 16 rows = 512 f4)
            const f4* src = xs4 + (size_t)(16 * wave) * 32;
            #pragma unroll
            for (int p = 0; p < 8; ++p) a[p] = src[lane + 64 * p];
        }
        for (int t = 0; t < nt64; ++t) {
            const int r0 = 64 * t + 16 * wave;

            // scatter regs -> LDS in output layout (+1 col shift)
            #pragma unroll
            for (int p = 0; p < 8; ++p) {
                const int q = lane + 64 * p;      // f4 index in 16x128 tile
                const int r = q >> 5;
                const int k = q & 31;
                float* d = &lb[r * 129 + 1 + 4 * k];
                d[0] = a[p].x; d[1] = a[p].y; d[2] = a[p].z; d[3] = a[p].w;
            }
            if (lane < 16) lb[lane * 129] = (float)(r0 + lane + 1) * invL;

            // software-prefetch next tile's loads (independent of drain below)
            if (t + 1 < nt64) {
                const f4* src = xs4 + (size_t)(64 * (t + 1) + 16 * wave) * 32;
                #pragma unroll
                for (int p = 0; p < 8; ++p) a[p] = src[lane + 64 * p];
            }

            // drain: flat LDS read + full-line cached stores
            const f4* __restrict__ l4 = (const f4*)lb;
            f4* __restrict__ o4 = (f4*)(os + (size_t)r0 * 129);
            #pragma unroll
            for (int p = 0; p < 8; ++p)
                o4[lane + 64 * p] = l4[lane + 64 * p];
            if (lane < 4)
                o4[512 + lane] = l4[512 + lane];
        }
    }

    // tail rows / unaligned segment base: scalar fallback (general ragged)
    const int e0 = nt64 * 64 * 129;
    const int E = L * 129;
    for (int e = e0 + tid; e < E; e += 256) {
        const int row = e / 129;
        const int c = e - row * 129;
        os[e] = (c == 0) ? (float)(row + 1) * invL
                         : xs[(size_t)row * 128 + (c - 1)];
    }
}

extern "C" void kernel_launch(void* const* d_in, const int* in_sizes, int n_in,
                              void* d_out, int out_size, void* d_ws, size_t ws_size,
                              hipStream_t stream) {
    const float* x = (const float*)d_in[0];
    const int* lengths = (const int*)d_in[1];
    const int n_seg = in_sizes[1];

    emb_kernel<<<n_seg, 256, 0, stream>>>(x, lengths, (float*)d_out);
}